// Round 8
// baseline (93.915 us; speedup 1.0000x reference)
//
#include <hip/hip_runtime.h>
#include <hip/hip_bf16.h>

#define VOCAB 50257
#define NTAGS 50
#define EMB   128
#define NTOK  262144
#define KD    640     // (2*CTX+1) * EMB
#define WPAD  64      // (fallback) tags padded to 4 MFMA tiles

#define TAGP  64      // per-position padded tag slots (slice = 128 B, line-aligned)
#define NZ    320     // 5 positions * TAGP
#define ZROWS 50304   // 3144*16 rows (rows >= VOCAB are zero sentinels)

#define TOK   64      // tokens per tag_k block
#define RWS   68      // staged rows (64 + 4 halo)
#define CHR   40      // 16B chunks per ZT row (640 B)
#define NCHUNK (RWS*CHR)          // 2720
#define NITER  ((NCHUNK+63)/64)   // 43

typedef __attribute__((ext_vector_type(4))) float f32x4;
typedef __attribute__((ext_vector_type(8))) short bf16x8;

__device__ __forceinline__ ushort f2bf(float f) {
    union { float f; unsigned u; } v; v.f = f;
    unsigned u = v.u;
    return (ushort)((u + 0x7fffu + ((u >> 16) & 1u)) >> 16);  // RNE
}

__device__ __forceinline__ void gload_lds16(const void* g, void* l) {
    __builtin_amdgcn_global_load_lds(
        (const __attribute__((address_space(1))) unsigned*)g,
        (__attribute__((address_space(3))) unsigned*)l, 16, 0, 0);
}

// ============================ primary path ============================
// Wt[n][d] bf16, n = p*64 + tag (tag>=50 zero); biasp[64] fp32 (pad 0)
__global__ void conv2_k(const float* __restrict__ W, const float* __restrict__ b,
                        ushort* __restrict__ Wt, float* __restrict__ biasp) {
    int i = blockIdx.x * blockDim.x + threadIdx.x;
    if (i < NZ * EMB / 4) {
        int j = i * 4;
        int n = j / EMB, d = j % EMB;
        int p = n >> 6, tg = n & 63;
        ushort4 o = {0, 0, 0, 0};
        if (tg < NTAGS) {
            float4 w4 = *(const float4*)(W + tg * KD + p * EMB + d);
            o = { f2bf(w4.x), f2bf(w4.y), f2bf(w4.z), f2bf(w4.w) };
        }
        *(ushort4*)(Wt + j) = o;
    } else {
        int k = i - NZ * EMB / 4;
        if (k < TAGP / 4) {
            #pragma unroll
            for (int e = 0; e < 4; ++e) {
                int j = k * 4 + e;
                biasp[j] = (j < NTAGS) ? b[j] : 0.f;
            }
        }
    }
}

// ZT[v][p*64+tag] = emb[v] . W[tag][p*128 : p*128+128]   (bf16 out)
// M=16 tiles: 3144 one-wave blocks (~12 waves/CU), emb read exactly once.
__global__ __launch_bounds__(64)
void zt_k(const float* __restrict__ emb, const ushort* __restrict__ Wt,
          ushort* __restrict__ ZT) {
    const int lane = threadIdx.x & 63;
    const int c = lane & 15, q = lane >> 4;
    const int vb = blockIdx.x * 16;
    const int row = vb + c;
    const bool ok = row < VOCAB;
    const float* rp = emb + (size_t)(ok ? row : 0) * EMB;

    bf16x8 A[4];
    #pragma unroll
    for (int kk = 0; kk < 4; ++kk) {
        float4 lo = {0,0,0,0}, hi = {0,0,0,0};
        if (ok) {
            lo = *(const float4*)(rp + kk * 32 + q * 8);
            hi = *(const float4*)(rp + kk * 32 + q * 8 + 4);
        }
        bf16x8 a;
        a[0]=(short)f2bf(lo.x); a[1]=(short)f2bf(lo.y);
        a[2]=(short)f2bf(lo.z); a[3]=(short)f2bf(lo.w);
        a[4]=(short)f2bf(hi.x); a[5]=(short)f2bf(hi.y);
        a[6]=(short)f2bf(hi.z); a[7]=(short)f2bf(hi.w);
        A[kk] = a;
    }

    #pragma unroll
    for (int ng = 0; ng < 5; ++ng) {        // ng == position p
        bf16x8 B[4][4];
        #pragma unroll
        for (int nt = 0; nt < 4; ++nt)
            #pragma unroll
            for (int kk = 0; kk < 4; ++kk)
                B[nt][kk] = *(const bf16x8*)(Wt + (ng * 64 + nt * 16 + c) * EMB
                                                + kk * 32 + q * 8);
        f32x4 acc[4];
        #pragma unroll
        for (int nt = 0; nt < 4; ++nt) acc[nt] = (f32x4){0.f,0.f,0.f,0.f};
        #pragma unroll
        for (int kk = 0; kk < 4; ++kk)
            #pragma unroll
            for (int nt = 0; nt < 4; ++nt)
                acc[nt] = __builtin_amdgcn_mfma_f32_16x16x32_bf16(
                    A[kk], B[nt][kk], acc[nt], 0, 0, 0);
        #pragma unroll
        for (int nt = 0; nt < 4; ++nt)
            #pragma unroll
            for (int j = 0; j < 4; ++j)
                ZT[(size_t)(vb + q * 4 + j) * NZ + ng * 64 + nt * 16 + c] =
                    f2bf(acc[nt][j]);
    }
}

// per 64-token block: coalesced-stage 68 ZT rows into LDS, window-sum slices,
// softmax, LDS-transpose for full-line output stores.
__global__ __launch_bounds__(64, 1)
void tag_k(const int* __restrict__ tokens, const ushort* __restrict__ ZT,
           const float* __restrict__ biasp, float* __restrict__ out) {
    __shared__ __align__(16) char smem[RWS * 640 + RWS * 4];   // rows + ids
    int* ids = (int*)(smem + RWS * 640);

    const int l  = threadIdx.x;
    const int bb = blockIdx.x * TOK;

    // ---- token ids for the 68 rows (row r <-> token bb-2+r) ----
    {
        int t = bb - 2 + l;
        ids[l] = (t >= 0 && t < NTOK) ? tokens[t] : VOCAB;   // VOCAB = zero row
        if (l < RWS - 64) {
            int t2 = bb + 62 + l;
            ids[64 + l] = (t2 >= 0 && t2 < NTOK) ? tokens[t2] : VOCAB;
        }
    }
    __syncthreads();

    // ---- read row ids (batched LDS reads, mostly broadcast) ----
    int tk[NITER];
    #pragma unroll
    for (int w = 0; w < NITER; ++w) {
        int g = w * 64 + l;
        int r = (g < NCHUNK) ? (g / CHR) : 0;
        tk[w] = ids[r];
    }

    // ---- coalesced stage: flat chunk g = r*40 + p*8 + i  ->  LDS byte g*16.
    //      source chunk pre-swizzled (i ^ (r&7)) so LDS dest stays linear. ----
    #pragma unroll
    for (int w = 0; w < NITER; ++w) {
        int g = w * 64 + l;
        if (g < NCHUNK) {
            int r  = g / CHR;
            int ch = g - r * CHR;
            int i  = ch & 7, p = ch >> 3;
            const char* src = (const char*)ZT + (size_t)tk[w] * 640
                              + p * 128 + ((i ^ (r & 7)) << 4);
            gload_lds16(src, smem + w * 1024);
        }
    }
    __syncthreads();

    // ---- accumulate bias + 5 window slices: slice p of token bb+l lives in
    //      LDS row l+p (token bb+l+p-2). ----
    float acc[56];
    #pragma unroll
    for (int g = 0; g < 14; ++g) {
        float4 b4 = *(const float4*)(biasp + g * 4);
        acc[g*4+0] = b4.x; acc[g*4+1] = b4.y; acc[g*4+2] = b4.z; acc[g*4+3] = b4.w;
    }
    {
        bf16x8 v[5][7];
        #pragma unroll
        for (int p = 0; p < 5; ++p) {
            const int rp = l + p;                 // LDS row for this slice
            const char* rb = smem + rp * 640;
            const int rx = (rp & 7) << 4;
            #pragma unroll
            for (int j = 0; j < 7; ++j)
                v[p][j] = *(const bf16x8*)(rb + p * 128 + ((j << 4) ^ rx));
        }
        #pragma unroll
        for (int p = 0; p < 5; ++p)
            #pragma unroll
            for (int j = 0; j < 7; ++j)
                #pragma unroll
                for (int e = 0; e < 8; ++e) {
                    unsigned u = (unsigned)(ushort)v[p][j][e] << 16;
                    acc[j*8+e] += __uint_as_float(u);
                }
    }

    // ---- log-softmax over tags 0..49 (all local to the lane) ----
    float m = acc[0];
    #pragma unroll
    for (int j = 1; j < NTAGS; ++j) m = fmaxf(m, acc[j]);
    float s = 0.f;
    #pragma unroll
    for (int j = 0; j < NTAGS; ++j) s += __expf(acc[j] - m);
    const float L = m + __logf(s);

    // ---- LDS transpose -> full-line coalesced stores ----
    __syncthreads();
    #pragma unroll
    for (int k = 0; k < 25; ++k) {
        float2 st = { acc[2*k] - L, acc[2*k+1] - L };
        *(float2*)(smem + (size_t)l * 200 + k * 8) = st;
    }
    __syncthreads();
    char* ob = (char*)out + (size_t)bb * 200;
    #pragma unroll
    for (int w = 0; w < 13; ++w) {
        if (w < 12 || l < 32) {
            f32x4 d = *(const f32x4*)(smem + w * 1024 + (size_t)l * 16);
            *(f32x4*)(ob + w * 1024 + (size_t)l * 16) = d;
        }
    }
}

// ============================ fallback path (R4, needs only ~13 MB ws) ============================
__global__ void fb_conv_k(const float* __restrict__ emb, const float* __restrict__ W,
                          ushort* __restrict__ embb, ushort* __restrict__ wb) {
    const int etotal = (VOCAB + 1) * EMB;
    int idx = (blockIdx.x * blockDim.x + threadIdx.x) * 4;
    if (idx < etotal) {
        float4 v = {0.f, 0.f, 0.f, 0.f};
        if (idx < VOCAB * EMB) v = *(const float4*)(emb + idx);
        ushort4 o = { f2bf(v.x), f2bf(v.y), f2bf(v.z), f2bf(v.w) };
        *(ushort4*)(embb + idx) = o;
    } else {
        int wi = idx - etotal;
        if (wi < WPAD * KD) {
            #pragma unroll
            for (int k = 0; k < 4; ++k) {
                int j = wi + k;
                int tag = j / KD;
                wb[j] = f2bf(tag < NTAGS ? W[j] : 0.f);
            }
        }
    }
}

__global__ __launch_bounds__(64, 2)
void fb_tag_k(const int* __restrict__ tokens, const ushort* __restrict__ embb,
              const ushort* __restrict__ Wb, const float* __restrict__ bias,
              float* __restrict__ out) {
    __shared__ ushort smem[68 * EMB];
    const int lane = threadIdx.x & 63;
    const int c = lane & 15;
    const int q = lane >> 4;
    const int bb = blockIdx.x * 64;
    const int rsub = lane >> 4;

    int tokid[17];
    #pragma unroll
    for (int g = 0; g < 17; ++g) {
        int t = bb - 2 + g * 4 + rsub;
        tokid[g] = (t >= 0 && t < NTOK) ? tokens[t] : VOCAB;
    }
    const ushort* bp[4];
    #pragma unroll
    for (int nt = 0; nt < 4; ++nt)
        bp[nt] = Wb + (nt * 16 + c) * KD + q * 8;
    bf16x8 Bb[4][4];
    #pragma unroll
    for (int s = 0; s < 4; ++s)
        #pragma unroll
        for (int nt = 0; nt < 4; ++nt)
            Bb[s][nt] = *(const bf16x8*)(bp[nt] + (s >> 2) * 128 + (s & 3) * 32);
    float bv[4];
    #pragma unroll
    for (int nt = 0; nt < 4; ++nt) {
        int tag = nt * 16 + c;
        bv[nt] = bias[tag < NTAGS ? tag : NTAGS - 1];
    }
    {
        const int pc = lane & 15;
        #pragma unroll
        for (int g = 0; g < 17; ++g) {
            int i = g * 4 + rsub;
            int sc = pc ^ (i & 7);
            gload_lds16(embb + (size_t)tokid[g] * EMB + sc * 8, (char*)smem + g * 1024);
        }
    }
    __syncthreads();

    f32x4 acc[4][4];
    #pragma unroll
    for (int mt = 0; mt < 4; ++mt)
        #pragma unroll
        for (int nt = 0; nt < 4; ++nt)
            acc[mt][nt] = (f32x4){0.f, 0.f, 0.f, 0.f};
    bf16x8 Ab[2][4];
    #pragma unroll
    for (int s = 0; s < 2; ++s) {
        int p = s >> 2, kk = s & 3;
        int ch = (4 * kk + q) ^ ((c + p) & 7);
        const char* ab = (const char*)smem + (c + p) * 256 + ch * 16;
        #pragma unroll
        for (int mt = 0; mt < 4; ++mt)
            Ab[s][mt] = *(const bf16x8*)(ab + mt * 4096);
    }
    #pragma unroll
    for (int s = 0; s < 20; ++s) {
        __builtin_amdgcn_s_setprio(1);
        #pragma unroll
        for (int mt = 0; mt < 4; ++mt)
            #pragma unroll
            for (int nt = 0; nt < 4; ++nt)
                acc[mt][nt] = __builtin_amdgcn_mfma_f32_16x16x32_bf16(
                    Ab[s & 1][mt], Bb[s & 3][nt], acc[mt][nt], 0, 0, 0);
        __builtin_amdgcn_s_setprio(0);
        if (s + 4 < 20) {
            const int tt = s + 4, p = tt >> 2, kk = tt & 3;
            #pragma unroll
            for (int nt = 0; nt < 4; ++nt)
                Bb[s & 3][nt] = *(const bf16x8*)(bp[nt] + p * 128 + kk * 32);
        }
        if (s + 2 < 20) {
            const int tt = s + 2, p = tt >> 2, kk = tt & 3;
            int ch = (4 * kk + q) ^ ((c + p) & 7);
            const char* ab = (const char*)smem + (c + p) * 256 + ch * 16;
            #pragma unroll
            for (int mt = 0; mt < 4; ++mt)
                Ab[s & 1][mt] = *(const bf16x8*)(ab + mt * 4096);
        }
    }
    #pragma unroll
    for (int mt = 0; mt < 4; ++mt) {
        #pragma unroll
        for (int j = 0; j < 4; ++j) {
            const int row = bb + mt * 16 + q * 4 + j;
            float x[4];
            float m = -1e30f;
            #pragma unroll
            for (int nt = 0; nt < 4; ++nt) {
                float xv = acc[mt][nt][j] + bv[nt];
                x[nt] = xv;
                if (nt * 16 + c < NTAGS) m = fmaxf(m, xv);
            }
            #pragma unroll
            for (int mask = 8; mask >= 1; mask >>= 1)
                m = fmaxf(m, __shfl_xor(m, mask));
            float s = 0.f;
            #pragma unroll
            for (int nt = 0; nt < 4; ++nt)
                if (nt * 16 + c < NTAGS) s += __expf(x[nt] - m);
            #pragma unroll
            for (int mask = 8; mask >= 1; mask >>= 1)
                s += __shfl_xor(s, mask);
            const float L = m + __logf(s);
            #pragma unroll
            for (int nt = 0; nt < 4; ++nt) {
                int tag = nt * 16 + c;
                if (tag < NTAGS) out[row * NTAGS + tag] = x[nt] - L;
            }
        }
    }
}

extern "C" void kernel_launch(void* const* d_in, const int* in_sizes, int n_in,
                              void* d_out, int out_size, void* d_ws, size_t ws_size,
                              hipStream_t stream) {
    const int*   tokens = (const int*)d_in[0];
    const float* emb    = (const float*)d_in[1];
    const float* W      = (const float*)d_in[2];
    const float* b      = (const float*)d_in[3];
    float* out = (float*)d_out;

    const size_t NEED = 82432ull + (size_t)ZROWS * NZ * 2ull;   // ~32.3 MB
    if (ws_size >= NEED) {
        ushort* Wt    = (ushort*)d_ws;                          // 320*128 bf16 (80 KB)
        float*  biasp = (float*)((char*)d_ws + 81920);          // 64 fp32
        ushort* ZT    = (ushort*)((char*)d_ws + 82432);         // ZROWS x 320 bf16
        conv2_k<<<41, 256, 0, stream>>>(W, b, Wt, biasp);
        zt_k<<<ZROWS / 16, 64, 0, stream>>>(emb, Wt, ZT);
        tag_k<<<NTOK / TOK, 64, 0, stream>>>(tokens, ZT, biasp, out);
    } else {
        ushort* embb = (ushort*)d_ws;
        ushort* Wb   = embb + (size_t)(VOCAB + 1) * EMB;
        const int etotal = (VOCAB + 1) * EMB;
        const int total4 = (etotal + WPAD * KD) / 4;
        fb_conv_k<<<(total4 + 255) / 256, 256, 0, stream>>>(emb, W, embb, Wb);
        fb_tag_k<<<NTOK / 64, 64, 0, stream>>>(tokens, embb, Wb, b, out);
    }
}

// Round 9
// 74.840 us; speedup vs baseline: 1.2549x; 1.2549x over previous
//
#include <hip/hip_runtime.h>
#include <hip/hip_bf16.h>

#define VOCAB 50257
#define NTAGS 50
#define EMB   128
#define NTOK  262144
#define KD    640     // (2*CTX+1) * EMB
#define WPAD  64      // (fallback) tags padded to 4 MFMA tiles

#define TAGP  64      // per-position padded tag slots (slice = 128 B, line-aligned)
#define NZ    320     // 5 positions * TAGP
#define ZROWS 50304   // 786*64 rows (rows >= VOCAB are zero sentinels)

#define TOK   64      // tokens per tag_k block
#define RWS   68      // staged rows (64 + 4 halo)
#define CHR   40      // 16B chunks per ZT row (640 B)
#define NCHUNK (RWS*CHR)          // 2720
#define NITER  ((NCHUNK+63)/64)   // 43

typedef __attribute__((ext_vector_type(4))) float f32x4;
typedef __attribute__((ext_vector_type(8))) short bf16x8;

__device__ __forceinline__ ushort f2bf(float f) {
    union { float f; unsigned u; } v; v.f = f;
    unsigned u = v.u;
    return (ushort)((u + 0x7fffu + ((u >> 16) & 1u)) >> 16);  // RNE
}

__device__ __forceinline__ void gload_lds16(const void* g, void* l) {
    __builtin_amdgcn_global_load_lds(
        (const __attribute__((address_space(1))) unsigned*)g,
        (__attribute__((address_space(3))) unsigned*)l, 16, 0, 0);
}

// ============================ primary path ============================
// Wt[n][d] bf16, n = p*64 + tag (tag>=50 zero); biasp[64] fp32 (pad 0)
__global__ void conv2_k(const float* __restrict__ W, const float* __restrict__ b,
                        ushort* __restrict__ Wt, float* __restrict__ biasp) {
    int i = blockIdx.x * blockDim.x + threadIdx.x;
    if (i < NZ * EMB / 4) {
        int j = i * 4;
        int n = j / EMB, d = j % EMB;
        int p = n >> 6, tg = n & 63;
        ushort4 o = {0, 0, 0, 0};
        if (tg < NTAGS) {
            float4 w4 = *(const float4*)(W + tg * KD + p * EMB + d);
            o = { f2bf(w4.x), f2bf(w4.y), f2bf(w4.z), f2bf(w4.w) };
        }
        *(ushort4*)(Wt + j) = o;
    } else {
        int k = i - NZ * EMB / 4;
        if (k < TAGP / 4) {
            #pragma unroll
            for (int e = 0; e < 4; ++e) {
                int j = k * 4 + e;
                biasp[j] = (j < NTAGS) ? b[j] : 0.f;
            }
        }
    }
}

// ZT[v][p*64+tag] = emb[v] . W[tag][p*128 : p*128+128]   (bf16 out)
// 786 blocks x 4 waves; Wt (80 KB) staged once per block into LDS.
__global__ __launch_bounds__(256)
void zt_k(const float* __restrict__ emb, const ushort* __restrict__ Wt,
          ushort* __restrict__ ZT) {
    __shared__ __align__(16) char wlds[NZ * EMB * 2];   // 80 KB, chunk-swizzled

    const int tid  = threadIdx.x;
    const int lane = tid & 63;
    const int wave = tid >> 6;
    const int c = lane & 15, q = lane >> 4;
    const int vb = blockIdx.x * 64;

    // ---- stage Wt into LDS: 5120 chunks of 16 B, 20 iters x 256 lanes.
    //      phys chunk j of row n holds logical chunk j^(n&7) (pre-swizzled src,
    //      LDS dest linear -> global_load_lds legal). ----
    #pragma unroll
    for (int it = 0; it < 20; ++it) {
        int g = it * 256 + tid;           // flat chunk = n*16 + j
        int n = g >> 4, j = g & 15;
        const char* src = (const char*)Wt + n * 256 + ((j ^ (n & 7)) << 4);
        gload_lds16(src, wlds + it * 4096 + wave * 1024);
    }

    // ---- A: this wave's 16 vocab rows, fp32 -> bf16 in regs ----
    const int row = vb + wave * 16 + c;
    const bool ok = row < VOCAB;
    const float* rp = emb + (size_t)(ok ? row : 0) * EMB;
    bf16x8 A[4];
    #pragma unroll
    for (int kk = 0; kk < 4; ++kk) {
        float4 lo = {0,0,0,0}, hi = {0,0,0,0};
        if (ok) {
            lo = *(const float4*)(rp + kk * 32 + q * 8);
            hi = *(const float4*)(rp + kk * 32 + q * 8 + 4);
        }
        bf16x8 a;
        a[0]=(short)f2bf(lo.x); a[1]=(short)f2bf(lo.y);
        a[2]=(short)f2bf(lo.z); a[3]=(short)f2bf(lo.w);
        a[4]=(short)f2bf(hi.x); a[5]=(short)f2bf(hi.y);
        a[6]=(short)f2bf(hi.z); a[7]=(short)f2bf(hi.w);
        A[kk] = a;
    }
    __syncthreads();

    #pragma unroll
    for (int ng = 0; ng < 5; ++ng) {        // ng == position p
        bf16x8 B[4][4];
        #pragma unroll
        for (int nt = 0; nt < 4; ++nt) {
            #pragma unroll
            for (int kk = 0; kk < 4; ++kk) {
                int r  = ng * 64 + nt * 16 + c;           // Wt row
                int ph = (kk * 4 + q) ^ (c & 7);          // phys chunk (r&7 == c&7)
                B[nt][kk] = *(const bf16x8*)(wlds + r * 256 + ph * 16);
            }
        }
        f32x4 acc[4];
        #pragma unroll
        for (int nt = 0; nt < 4; ++nt) acc[nt] = (f32x4){0.f,0.f,0.f,0.f};
        #pragma unroll
        for (int kk = 0; kk < 4; ++kk)
            #pragma unroll
            for (int nt = 0; nt < 4; ++nt)
                acc[nt] = __builtin_amdgcn_mfma_f32_16x16x32_bf16(
                    A[kk], B[nt][kk], acc[nt], 0, 0, 0);
        #pragma unroll
        for (int nt = 0; nt < 4; ++nt)
            #pragma unroll
            for (int j = 0; j < 4; ++j)
                ZT[(size_t)(vb + wave * 16 + q * 4 + j) * NZ + ng * 64 + nt * 16 + c] =
                    f2bf(acc[nt][j]);
    }
}

// per 64-token block: reg-stage 68 ZT rows into LDS (coalesced loads, swizzled
// ds_write), window-sum slices, softmax, LDS-transpose full-line stores.
__global__ __launch_bounds__(64, 3)
void tag_k(const int* __restrict__ tokens, const ushort* __restrict__ ZT,
           const float* __restrict__ biasp, float* __restrict__ out) {
    __shared__ __align__(16) char smem[RWS * 640 + RWS * 4];   // rows + ids
    int* ids = (int*)(smem + RWS * 640);

    const int l  = threadIdx.x;
    const int bb = blockIdx.x * TOK;

    // ---- token ids for the 68 rows (row r <-> token bb-2+r) ----
    {
        int t = bb - 2 + l;
        ids[l] = (t >= 0 && t < NTOK) ? tokens[t] : VOCAB;   // VOCAB = zero row
        if (l < RWS - 64) {
            int t2 = bb + 62 + l;
            ids[64 + l] = (t2 >= 0 && t2 < NTOK) ? tokens[t2] : VOCAB;
        }
    }
    __syncthreads();

    // ---- reg-staging in 4 rounds: linear global f32x4 loads -> swizzled
    //      ds_write_b128.  flat chunk g = r*40 + p*8 + i ;
    //      phys chunk i^(r&7) within slice p of LDS row r. ----
    #pragma unroll
    for (int rd = 0; rd < 4; ++rd) {
        const int w0 = rd * 11;
        const int w1 = (rd == 3) ? NITER : (w0 + 11);
        f32x4 buf[11];
        #pragma unroll
        for (int w = w0; w < w1; ++w) {
            int g = w * 64 + l;
            bool okg = g < NCHUNK;
            int r  = okg ? (g / CHR) : 0;
            int ch = g - r * CHR;
            buf[w - w0] = okg
                ? *(const f32x4*)((const char*)ZT + (size_t)ids[r] * 640 + ch * 16)
                : (f32x4){0.f,0.f,0.f,0.f};
        }
        #pragma unroll
        for (int w = w0; w < w1; ++w) {
            int g = w * 64 + l;
            if (g < NCHUNK) {
                int r  = g / CHR;
                int ch = g - r * CHR;
                int i  = ch & 7, p = ch >> 3;
                *(f32x4*)(smem + r * 640 + p * 128 + ((i ^ (r & 7)) << 4)) = buf[w - w0];
            }
        }
    }
    __syncthreads();

    // ---- accumulate bias + 5 window slices: slice p of token bb+l lives in
    //      LDS row l+p (token bb+l+p-2). ----
    float acc[56];
    #pragma unroll
    for (int g = 0; g < 14; ++g) {
        float4 b4 = *(const float4*)(biasp + g * 4);
        acc[g*4+0] = b4.x; acc[g*4+1] = b4.y; acc[g*4+2] = b4.z; acc[g*4+3] = b4.w;
    }
    {
        bf16x8 v[5][7];
        #pragma unroll
        for (int p = 0; p < 5; ++p) {
            const int rp = l + p;                 // LDS row for this slice
            const char* rb = smem + rp * 640;
            const int rx = (rp & 7) << 4;
            #pragma unroll
            for (int j = 0; j < 7; ++j)
                v[p][j] = *(const bf16x8*)(rb + p * 128 + ((j << 4) ^ rx));
        }
        #pragma unroll
        for (int p = 0; p < 5; ++p)
            #pragma unroll
            for (int j = 0; j < 7; ++j)
                #pragma unroll
                for (int e = 0; e < 8; ++e) {
                    unsigned u = (unsigned)(ushort)v[p][j][e] << 16;
                    acc[j*8+e] += __uint_as_float(u);
                }
    }

    // ---- log-softmax over tags 0..49 (all local to the lane) ----
    float m = acc[0];
    #pragma unroll
    for (int j = 1; j < NTAGS; ++j) m = fmaxf(m, acc[j]);
    float s = 0.f;
    #pragma unroll
    for (int j = 0; j < NTAGS; ++j) s += __expf(acc[j] - m);
    const float L = m + __logf(s);

    // ---- LDS transpose -> full-line coalesced stores ----
    __syncthreads();
    #pragma unroll
    for (int k = 0; k < 25; ++k) {
        float2 st = { acc[2*k] - L, acc[2*k+1] - L };
        *(float2*)(smem + (size_t)l * 200 + k * 8) = st;
    }
    __syncthreads();
    char* ob = (char*)out + (size_t)bb * 200;
    #pragma unroll
    for (int w = 0; w < 13; ++w) {
        if (w < 12 || l < 32) {
            f32x4 d = *(const f32x4*)(smem + w * 1024 + (size_t)l * 16);
            *(f32x4*)(ob + w * 1024 + (size_t)l * 16) = d;
        }
    }
}

// ============================ fallback path (R4, needs only ~13 MB ws) ============================
__global__ void fb_conv_k(const float* __restrict__ emb, const float* __restrict__ W,
                          ushort* __restrict__ embb, ushort* __restrict__ wb) {
    const int etotal = (VOCAB + 1) * EMB;
    int idx = (blockIdx.x * blockDim.x + threadIdx.x) * 4;
    if (idx < etotal) {
        float4 v = {0.f, 0.f, 0.f, 0.f};
        if (idx < VOCAB * EMB) v = *(const float4*)(emb + idx);
        ushort4 o = { f2bf(v.x), f2bf(v.y), f2bf(v.z), f2bf(v.w) };
        *(ushort4*)(embb + idx) = o;
    } else {
        int wi = idx - etotal;
        if (wi < WPAD * KD) {
            #pragma unroll
            for (int k = 0; k < 4; ++k) {
                int j = wi + k;
                int tag = j / KD;
                wb[j] = f2bf(tag < NTAGS ? W[j] : 0.f);
            }
        }
    }
}

__global__ __launch_bounds__(64, 2)
void fb_tag_k(const int* __restrict__ tokens, const ushort* __restrict__ embb,
              const ushort* __restrict__ Wb, const float* __restrict__ bias,
              float* __restrict__ out) {
    __shared__ ushort smem[68 * EMB];
    const int lane = threadIdx.x & 63;
    const int c = lane & 15;
    const int q = lane >> 4;
    const int bb = blockIdx.x * 64;
    const int rsub = lane >> 4;

    int tokid[17];
    #pragma unroll
    for (int g = 0; g < 17; ++g) {
        int t = bb - 2 + g * 4 + rsub;
        tokid[g] = (t >= 0 && t < NTOK) ? tokens[t] : VOCAB;
    }
    const ushort* bp[4];
    #pragma unroll
    for (int nt = 0; nt < 4; ++nt)
        bp[nt] = Wb + (nt * 16 + c) * KD + q * 8;
    bf16x8 Bb[4][4];
    #pragma unroll
    for (int s = 0; s < 4; ++s)
        #pragma unroll
        for (int nt = 0; nt < 4; ++nt)
            Bb[s][nt] = *(const bf16x8*)(bp[nt] + (s >> 2) * 128 + (s & 3) * 32);
    float bv[4];
    #pragma unroll
    for (int nt = 0; nt < 4; ++nt) {
        int tag = nt * 16 + c;
        bv[nt] = bias[tag < NTAGS ? tag : NTAGS - 1];
    }
    {
        const int pc = lane & 15;
        #pragma unroll
        for (int g = 0; g < 17; ++g) {
            int i = g * 4 + rsub;
            int sc = pc ^ (i & 7);
            gload_lds16(embb + (size_t)tokid[g] * EMB + sc * 8, (char*)smem + g * 1024);
        }
    }
    __syncthreads();

    f32x4 acc[4][4];
    #pragma unroll
    for (int mt = 0; mt < 4; ++mt)
        #pragma unroll
        for (int nt = 0; nt < 4; ++nt)
            acc[mt][nt] = (f32x4){0.f, 0.f, 0.f, 0.f};
    bf16x8 Ab[2][4];
    #pragma unroll
    for (int s = 0; s < 2; ++s) {
        int p = s >> 2, kk = s & 3;
        int ch = (4 * kk + q) ^ ((c + p) & 7);
        const char* ab = (const char*)smem + (c + p) * 256 + ch * 16;
        #pragma unroll
        for (int mt = 0; mt < 4; ++mt)
            Ab[s][mt] = *(const bf16x8*)(ab + mt * 4096);
    }
    #pragma unroll
    for (int s = 0; s < 20; ++s) {
        __builtin_amdgcn_s_setprio(1);
        #pragma unroll
        for (int mt = 0; mt < 4; ++mt)
            #pragma unroll
            for (int nt = 0; nt < 4; ++nt)
                acc[mt][nt] = __builtin_amdgcn_mfma_f32_16x16x32_bf16(
                    Ab[s & 1][mt], Bb[s & 3][nt], acc[mt][nt], 0, 0, 0);
        __builtin_amdgcn_s_setprio(0);
        if (s + 4 < 20) {
            const int tt = s + 4, p = tt >> 2, kk = tt & 3;
            #pragma unroll
            for (int nt = 0; nt < 4; ++nt)
                Bb[s & 3][nt] = *(const bf16x8*)(bp[nt] + p * 128 + kk * 32);
        }
        if (s + 2 < 20) {
            const int tt = s + 2, p = tt >> 2, kk = tt & 3;
            int ch = (4 * kk + q) ^ ((c + p) & 7);
            const char* ab = (const char*)smem + (c + p) * 256 + ch * 16;
            #pragma unroll
            for (int mt = 0; mt < 4; ++mt)
                Ab[s & 1][mt] = *(const bf16x8*)(ab + mt * 4096);
        }
    }
    #pragma unroll
    for (int mt = 0; mt < 4; ++mt) {
        #pragma unroll
        for (int j = 0; j < 4; ++j) {
            const int row = bb + mt * 16 + q * 4 + j;
            float x[4];
            float m = -1e30f;
            #pragma unroll
            for (int nt = 0; nt < 4; ++nt) {
                float xv = acc[mt][nt][j] + bv[nt];
                x[nt] = xv;
                if (nt * 16 + c < NTAGS) m = fmaxf(m, xv);
            }
            #pragma unroll
            for (int mask = 8; mask >= 1; mask >>= 1)
                m = fmaxf(m, __shfl_xor(m, mask));
            float s = 0.f;
            #pragma unroll
            for (int nt = 0; nt < 4; ++nt)
                if (nt * 16 + c < NTAGS) s += __expf(x[nt] - m);
            #pragma unroll
            for (int mask = 8; mask >= 1; mask >>= 1)
                s += __shfl_xor(s, mask);
            const float L = m + __logf(s);
            #pragma unroll
            for (int nt = 0; nt < 4; ++nt) {
                int tag = nt * 16 + c;
                if (tag < NTAGS) out[row * NTAGS + tag] = x[nt] - L;
            }
        }
    }
}

extern "C" void kernel_launch(void* const* d_in, const int* in_sizes, int n_in,
                              void* d_out, int out_size, void* d_ws, size_t ws_size,
                              hipStream_t stream) {
    const int*   tokens = (const int*)d_in[0];
    const float* emb    = (const float*)d_in[1];
    const float* W      = (const float*)d_in[2];
    const float* b      = (const float*)d_in[3];
    float* out = (float*)d_out;

    const size_t NEED = 82432ull + (size_t)ZROWS * NZ * 2ull;   // ~32.3 MB
    if (ws_size >= NEED) {
        ushort* Wt    = (ushort*)d_ws;                          // 320*128 bf16 (80 KB)
        float*  biasp = (float*)((char*)d_ws + 81920);          // 64 fp32
        ushort* ZT    = (ushort*)((char*)d_ws + 82432);         // ZROWS x 320 bf16
        conv2_k<<<41, 256, 0, stream>>>(W, b, Wt, biasp);
        zt_k<<<ZROWS / 64, 256, 0, stream>>>(emb, Wt, ZT);
        tag_k<<<NTOK / TOK, 64, 0, stream>>>(tokens, ZT, biasp, out);
    } else {
        ushort* embb = (ushort*)d_ws;
        ushort* Wb   = embb + (size_t)(VOCAB + 1) * EMB;
        const int etotal = (VOCAB + 1) * EMB;
        const int total4 = (etotal + WPAD * KD) / 4;
        fb_conv_k<<<(total4 + 255) / 256, 256, 0, stream>>>(emb, W, embb, Wb);
        fb_tag_k<<<NTOK / 64, 64, 0, stream>>>(tokens, embb, Wb, b, out);
    }
}